// Round 6
// baseline (867.971 us; speedup 1.0000x reference)
//
#include <hip/hip_runtime.h>
#include <hip/hip_bf16.h>
#include <math.h>

// Problem constants: N=100000, E=600000, D=128, H=4, F=32, L=3

__device__ __forceinline__ float leaky02(float x) {
    return x >= 0.f ? x : 0.2f * x;
}

// ---------------------------------------------------------------------------
// CSR build
__global__ __launch_bounds__(256) void deg_init_kernel(int* __restrict__ deg, int N)
{
    int i = blockIdx.x * 256 + threadIdx.x;
    if (i < N) deg[i] = 1;  // self loop
}

__global__ __launch_bounds__(256) void deg_count_kernel(
    const int* __restrict__ dst, int* __restrict__ deg, int E)
{
    int i = blockIdx.x * 256 + threadIdx.x;
    if (i < E) atomicAdd(&deg[dst[i]], 1);
}

#define SCAN_TILE 1024

__global__ __launch_bounds__(256) void scanA_kernel(
    const int* __restrict__ deg, int* __restrict__ bsum, int N)
{
    __shared__ int ws[4];
    int b = blockIdx.x, t = threadIdx.x;
    int base = b * SCAN_TILE + t * 4;
    int s = 0;
#pragma unroll
    for (int k = 0; k < 4; ++k) {
        int i = base + k;
        if (i < N) s += deg[i];
    }
#pragma unroll
    for (int m = 32; m >= 1; m >>= 1) s += __shfl_xor(s, m, 64);
    if ((t & 63) == 0) ws[t >> 6] = s;
    __syncthreads();
    if (t == 0) bsum[b] = ws[0] + ws[1] + ws[2] + ws[3];
}

__global__ __launch_bounds__(1024) void scanB_kernel(
    int* __restrict__ bsum, int* __restrict__ bpre, int* __restrict__ rowp,
    int NB, int N)
{
    __shared__ int sh[1024];
    int t = threadIdx.x;
    int v = (t < NB) ? bsum[t] : 0;
    sh[t] = v;
    __syncthreads();
    for (int off = 1; off < 1024; off <<= 1) {
        int u = (t >= off) ? sh[t - off] : 0;
        __syncthreads();
        sh[t] += u;
        __syncthreads();
    }
    if (t < NB) bpre[t] = sh[t] - v;          // exclusive prefix
    if (t == 1023) rowp[N] = sh[1023];        // total
}

__global__ __launch_bounds__(256) void scanC_kernel(
    const int* __restrict__ deg, const int* __restrict__ bpre,
    int* __restrict__ rowp, int* __restrict__ cur, int N)
{
    __shared__ int sh[256];
    int b = blockIdx.x, t = threadIdx.x;
    int base = b * SCAN_TILE + t * 4;
    int v[4];
#pragma unroll
    for (int k = 0; k < 4; ++k) {
        int i = base + k;
        v[k] = (i < N) ? deg[i] : 0;
    }
    int tsum = v[0] + v[1] + v[2] + v[3];
    sh[t] = tsum;
    __syncthreads();
    for (int off = 1; off < 256; off <<= 1) {
        int u = (t >= off) ? sh[t - off] : 0;
        __syncthreads();
        sh[t] += u;
        __syncthreads();
    }
    int pre = bpre[b] + sh[t] - tsum;
#pragma unroll
    for (int k = 0; k < 4; ++k) {
        int i = base + k;
        if (i < N) { rowp[i] = pre; cur[i] = pre; }
        pre += v[k];
    }
}

__global__ __launch_bounds__(256) void scatter_kernel(
    const int* __restrict__ src, const int* __restrict__ dst,
    int* __restrict__ cur, int* __restrict__ col, int E, int N)
{
    int i = blockIdx.x * 256 + threadIdx.x;
    if (i < E) {
        int p = atomicAdd(&cur[dst[i]], 1);
        col[p] = src[i];
    } else if (i < E + N) {
        int v = i - E;
        int p = atomicAdd(&cur[v], 1);
        col[p] = v;  // self loop
    }
}

// ---------------------------------------------------------------------------
// Layer-0 rank-1 precompute
__global__ __launch_bounds__(128) void rank1_prep_kernel(
    const float* __restrict__ lW, const float* __restrict__ lb,
    const float* __restrict__ W0, const float* __restrict__ al,
    const float* __restrict__ ar, float* __restrict__ c1,
    float* __restrict__ c2, float* __restrict__ prm)
{
    int j = threadIdx.x;
    float s1 = 0.f, s2 = 0.f;
    for (int d = 0; d < 128; ++d) {
        float wv = W0[j * 128 + d];
        s1 += lW[d] * wv;
        s2 += lb[d] * wv;
    }
    c1[j] = s1; c2[j] = s2;
    __shared__ float sh1[128], sh2[128], sh3[128], sh4[128];
    sh1[j] = s1 * al[j]; sh2[j] = s2 * al[j];
    sh3[j] = s1 * ar[j]; sh4[j] = s2 * ar[j];
    __syncthreads();
    if (j < 4) {
        float p = 0.f, q = 0.f, r = 0.f, s = 0.f;
        for (int f = 0; f < 32; ++f) {
            p += sh1[j * 32 + f]; q += sh2[j * 32 + f];
            r += sh3[j * 32 + f]; s += sh4[j * 32 + f];
        }
        prm[j] = p; prm[4 + j] = q; prm[8 + j] = r; prm[12 + j] = s;
    }
}

// h0[n,j] = w[n]*c1[j] + c2[j]; el0[n,h] = w[n]*pl[h]+ql[h]; er0 likewise.
__global__ __launch_bounds__(256) void rank1_apply_kernel(
    const float* __restrict__ w, const float* __restrict__ c1,
    const float* __restrict__ c2, const float* __restrict__ prm,
    float* __restrict__ h, float* __restrict__ el, float* __restrict__ er, int N)
{
    int i = blockIdx.x * 256 + threadIdx.x;
    int n = i >> 5, k = i & 31;
    if (n >= N) return;
    float wn = w[n];
    float4 a = *reinterpret_cast<const float4*>(&c1[k * 4]);
    float4 b = *reinterpret_cast<const float4*>(&c2[k * 4]);
    float4 o = make_float4(wn * a.x + b.x, wn * a.y + b.y,
                           wn * a.z + b.z, wn * a.w + b.w);
    *reinterpret_cast<float4*>(&h[(size_t)n * 128 + k * 4]) = o;
    if (k == 0) {
        float4 pl = *reinterpret_cast<const float4*>(&prm[0]);
        float4 ql = *reinterpret_cast<const float4*>(&prm[4]);
        float4 pr = *reinterpret_cast<const float4*>(&prm[8]);
        float4 qr = *reinterpret_cast<const float4*>(&prm[12]);
        float4 e1 = make_float4(wn * pl.x + ql.x, wn * pl.y + ql.y,
                                wn * pl.z + ql.z, wn * pl.w + ql.w);
        float4 e2 = make_float4(wn * pr.x + qr.x, wn * pr.y + qr.y,
                                wn * pr.z + qr.z, wn * pr.w + qr.w);
        *reinterpret_cast<float4*>(&el[(size_t)n * 4]) = e1;
        *reinterpret_cast<float4*>(&er[(size_t)n * 4]) = e2;
    }
}

// ---------------------------------------------------------------------------
// GEMM + fused el/er (layers 1,2): h[n,j] = sum_d leaky0.01(x[n,d])*W[j,d];
// el[n,hd] = sum_f h[n,hd,f]*al[hd,f]; er likewise.
// NO LDS: W (64 KB) is L1/L2-resident and read via broadcast-coalesced
// float4 loads; x rows read per-thread. Block = 256 thr, tile 128x128.
// Thread (tx=tid&7, ty=tid>>3): rows m0+ty*4..+3, cols tx*16..+15.
// Note: each thread's 16 cols lie within ONE head (head = tx>>1), so el/er
// partials reduce with a single shfl_xor(1) pair-combine.
__global__ __launch_bounds__(256) void gemm_fused_kernel(
    const float* __restrict__ x, const float* __restrict__ W,
    const float* __restrict__ al, const float* __restrict__ ar,
    float* __restrict__ h, float* __restrict__ el, float* __restrict__ er,
    int N)
{
    const int tid = threadIdx.x;
    const int tx = tid & 7;
    const int ty = tid >> 3;
    const int m0 = blockIdx.x * 128;
    const int c0 = tx * 16;

    float acc[4][16];
#pragma unroll
    for (int r = 0; r < 4; ++r)
#pragma unroll
        for (int c = 0; c < 16; ++c) acc[r][c] = 0.f;

    // clamped row base pointers (loads stay in-bounds; stores are guarded)
    const float* xr[4];
#pragma unroll
    for (int r = 0; r < 4; ++r) {
        int row = m0 + ty * 4 + r;
        if (row > N - 1) row = N - 1;
        xr[r] = x + (size_t)row * 128;
    }

    for (int d0 = 0; d0 < 128; d0 += 4) {
        float4 a[4];
#pragma unroll
        for (int r = 0; r < 4; ++r) {
            float4 v = *reinterpret_cast<const float4*>(xr[r] + d0);
            v.x = v.x >= 0.f ? v.x : 0.01f * v.x;
            v.y = v.y >= 0.f ? v.y : 0.01f * v.y;
            v.z = v.z >= 0.f ? v.z : 0.01f * v.z;
            v.w = v.w >= 0.f ? v.w : 0.01f * v.w;
            a[r] = v;
        }
#pragma unroll
        for (int c = 0; c < 16; ++c) {
            const float4 b = *reinterpret_cast<const float4*>(&W[(size_t)(c0 + c) * 128 + d0]);
#pragma unroll
            for (int r = 0; r < 4; ++r) {
                acc[r][c] += a[r].x * b.x + a[r].y * b.y
                           + a[r].z * b.z + a[r].w * b.w;
            }
        }
    }

    // epilogue: store h, fused el/er
    const int head = tx >> 1;
#pragma unroll
    for (int r = 0; r < 4; ++r) {
        int row = m0 + ty * 4 + r;
        bool ok = row < N;   // partner lane (tx^1) has same row -> no shfl divergence
        if (ok) {
#pragma unroll
            for (int c4 = 0; c4 < 16; c4 += 4) {
                float4 v = make_float4(acc[r][c4], acc[r][c4 + 1],
                                       acc[r][c4 + 2], acc[r][c4 + 3]);
                *reinterpret_cast<float4*>(&h[(size_t)row * 128 + c0 + c4]) = v;
            }
        }
        float elp = 0.f, erp = 0.f;
#pragma unroll
        for (int c = 0; c < 16; ++c) {
            elp += acc[r][c] * al[c0 + c];
            erp += acc[r][c] * ar[c0 + c];
        }
        elp += __shfl_xor(elp, 1, 64);
        erp += __shfl_xor(erp, 1, 64);
        if (ok && (tx & 1) == 0) {
            el[(size_t)row * 4 + head] = elp;
            er[(size_t)row * 4 + head] = erp;
        }
    }
}

// ---------------------------------------------------------------------------
// Fused softmax-stats + gather + (optional) prediction epilogue.
// One wave per node (see R4 notes: head-quartered Phase A, direct-load
// Phase B with 4 edges in flight).
__global__ __launch_bounds__(256) void agg_fused_kernel(
    const float* __restrict__ h, const float* __restrict__ el,
    const float* __restrict__ er, const int* __restrict__ rowp,
    const int* __restrict__ col, const float* __restrict__ bias,
    float* __restrict__ xout, const float* __restrict__ pW,
    const float* __restrict__ pb, float* __restrict__ logits,
    int N, int last)
{
    int v = blockIdx.x * 4 + (threadIdx.x >> 6);
    int lane = threadIdx.x & 63;
    if (v >= N) return;
    const int r0 = rowp[v], r1 = rowp[v + 1];
    const int deg = r1 - r0;

    // ---- Phase A: per-head online softmax stats
    const int qh  = lane >> 4;
    const int j16 = lane & 15;
    const float erq = er[(size_t)v * 4 + qh];

    float m_l = -INFINITY, s_l = 0.f;
    for (int jj = j16; jj < deg; jj += 16) {
        int u = col[r0 + jj];
        float e = leaky02(el[(size_t)u * 4 + qh] + erq);
        if (e > m_l) { s_l = s_l * __expf(m_l - e) + 1.f; m_l = e; }
        else         { s_l += __expf(e - m_l); }
    }
#pragma unroll
    for (int d = 1; d <= 8; d <<= 1) {
        float m2 = __shfl_xor(m_l, d, 64);
        float s2 = __shfl_xor(s_l, d, 64);
        float nm = fmaxf(m_l, m2);
        s_l = (s_l > 0.f ? s_l * __expf(m_l - nm) : 0.f)
            + (s2  > 0.f ? s2  * __expf(m2  - nm) : 0.f);
        m_l = nm;
    }
    const float is_l = 1.f / s_l;

    // ---- Phase B: gather, 4 edges in flight (quarter-wave per edge)
    const int q = lane >> 4, l16 = lane & 15, f0 = l16 * 4, hA = l16 >> 3;
    const float mA  = __shfl(m_l,  hA * 16, 64);
    const float isA = __shfl(is_l, hA * 16, 64);
    const float mB  = __shfl(m_l,  (hA + 2) * 16, 64);
    const float isB = __shfl(is_l, (hA + 2) * 16, 64);
    const float erA = er[(size_t)v * 4 + hA];
    const float erB = er[(size_t)v * 4 + 2 + hA];

    float4 acc0 = make_float4(0.f, 0.f, 0.f, 0.f);
    float4 acc1 = make_float4(0.f, 0.f, 0.f, 0.f);

    for (int j = r0 + q; j < r1; j += 4) {
        int u = col[j];
        float eA = leaky02(el[(size_t)u * 4 + hA] + erA);
        float eB = leaky02(el[(size_t)u * 4 + 2 + hA] + erB);
        float aA = __expf(eA - mA) * isA;
        float aB = __expf(eB - mB) * isB;
        const float4 v0 = *reinterpret_cast<const float4*>(&h[(size_t)u * 128 + f0]);
        const float4 v1 = *reinterpret_cast<const float4*>(&h[(size_t)u * 128 + 64 + f0]);
        acc0.x += aA * v0.x; acc0.y += aA * v0.y;
        acc0.z += aA * v0.z; acc0.w += aA * v0.w;
        acc1.x += aB * v1.x; acc1.y += aB * v1.y;
        acc1.z += aB * v1.z; acc1.w += aB * v1.w;
    }

#pragma unroll
    for (int d = 16; d <= 32; d <<= 1) {
        acc0.x += __shfl_xor(acc0.x, d, 64);
        acc0.y += __shfl_xor(acc0.y, d, 64);
        acc0.z += __shfl_xor(acc0.z, d, 64);
        acc0.w += __shfl_xor(acc0.w, d, 64);
        acc1.x += __shfl_xor(acc1.x, d, 64);
        acc1.y += __shfl_xor(acc1.y, d, 64);
        acc1.z += __shfl_xor(acc1.z, d, 64);
        acc1.w += __shfl_xor(acc1.w, d, 64);
    }

    if (last) {
        float part = 0.f;
        if (lane < 16) {
            float4 b0 = *reinterpret_cast<const float4*>(&bias[f0]);
            float4 b1 = *reinterpret_cast<const float4*>(&bias[64 + f0]);
            float4 p0 = *reinterpret_cast<const float4*>(&pW[f0]);
            float4 p1 = *reinterpret_cast<const float4*>(&pW[64 + f0]);
            part = (acc0.x + b0.x) * p0.x + (acc0.y + b0.y) * p0.y
                 + (acc0.z + b0.z) * p0.z + (acc0.w + b0.w) * p0.w
                 + (acc1.x + b1.x) * p1.x + (acc1.y + b1.y) * p1.y
                 + (acc1.z + b1.z) * p1.z + (acc1.w + b1.w) * p1.w;
        }
#pragma unroll
        for (int d = 8; d >= 1; d >>= 1) part += __shfl_xor(part, d, 64);
        if (lane == 0) logits[v] = part + pb[0];
    } else {
        if (lane < 16) {
            float4 b0 = *reinterpret_cast<const float4*>(&bias[f0]);
            float4 b1 = *reinterpret_cast<const float4*>(&bias[64 + f0]);
            acc0.x += b0.x; acc0.y += b0.y; acc0.z += b0.z; acc0.w += b0.w;
            acc1.x += b1.x; acc1.y += b1.y; acc1.z += b1.z; acc1.w += b1.w;
            *reinterpret_cast<float4*>(&xout[(size_t)v * 128 + f0])      = acc0;
            *reinterpret_cast<float4*>(&xout[(size_t)v * 128 + 64 + f0]) = acc1;
        }
    }
}

// ---------------------------------------------------------------------------
extern "C" void kernel_launch(void* const* d_in, const int* in_sizes, int n_in,
                              void* d_out, int out_size, void* d_ws, size_t ws_size,
                              hipStream_t stream)
{
    const float* weights = (const float*)d_in[0];
    const float* lin_W   = (const float*)d_in[1];
    const float* lin_b   = (const float*)d_in[2];
    const float* fc_W    = (const float*)d_in[3];
    const float* attn_l  = (const float*)d_in[4];
    const float* attn_r  = (const float*)d_in[5];
    const float* conv_b  = (const float*)d_in[6];
    const float* pred_W  = (const float*)d_in[7];
    const float* pred_b  = (const float*)d_in[8];
    const int*   src     = (const int*)d_in[9];
    const int*   dst     = (const int*)d_in[10];

    const int N = in_sizes[0];
    const int E = in_sizes[9];
    const int NB = (N + SCAN_TILE - 1) / SCAN_TILE;

    // workspace layout (16B-aligned float4 sections first)
    float* x   = (float*)d_ws;                   // N*128
    float* h   = x + (size_t)N * 128;            // N*128
    float* el  = h + (size_t)N * 128;            // N*4
    float* er  = el + (size_t)N * 4;             // N*4
    float* c1  = er + (size_t)N * 4;             // 128
    float* c2  = c1 + 128;                       // 128
    float* prm = c2 + 128;                       // 16
    int*   deg  = (int*)(prm + 16);              // N
    int*   rowp = deg + N;                       // N+1
    int*   cur  = rowp + (N + 1);                // N
    int*   col  = cur + N;                       // E+N
    int*   bsum = col + (E + N);                 // NB
    int*   bpre = bsum + NB;                     // NB

    // CSR build (fresh every call: ws is re-poisoned)
    deg_init_kernel<<<(N + 255) / 256, 256, 0, stream>>>(deg, N);
    deg_count_kernel<<<(E + 255) / 256, 256, 0, stream>>>(dst, deg, E);
    scanA_kernel<<<NB, 256, 0, stream>>>(deg, bsum, N);
    scanB_kernel<<<1, 1024, 0, stream>>>(bsum, bpre, rowp, NB, N);
    scanC_kernel<<<NB, 256, 0, stream>>>(deg, bpre, rowp, cur, N);
    scatter_kernel<<<(E + N + 255) / 256, 256, 0, stream>>>(src, dst, cur, col, E, N);

    // Layer 0 via rank-1 identity
    rank1_prep_kernel<<<1, 128, 0, stream>>>(lin_W, lin_b, fc_W, attn_l, attn_r,
                                             c1, c2, prm);
    rank1_apply_kernel<<<((size_t)N * 32 + 255) / 256, 256, 0, stream>>>(
        weights, c1, c2, prm, h, el, er, N);
    agg_fused_kernel<<<(N + 3) / 4, 256, 0, stream>>>(
        h, el, er, rowp, col, conv_b, x, pred_W, pred_b, (float*)d_out, N, 0);

    // Layers 1, 2 (gemm with fused el/er epilogue)
    for (int l = 1; l < 3; ++l) {
        gemm_fused_kernel<<<(N + 127) / 128, 256, 0, stream>>>(
            x, fc_W + (size_t)l * 128 * 128,
            attn_l + l * 128, attn_r + l * 128,
            h, el, er, N);
        agg_fused_kernel<<<(N + 3) / 4, 256, 0, stream>>>(
            h, el, er, rowp, col, conv_b + l * 128, x, pred_W, pred_b,
            (float*)d_out, N, l == 2 ? 1 : 0);
    }
}

// Round 7
// 533.308 us; speedup vs baseline: 1.6275x; 1.6275x over previous
//
#include <hip/hip_runtime.h>
#include <hip/hip_bf16.h>
#include <math.h>

// Problem constants: N=100000, E=600000, D=128, H=4, F=32, L=3

__device__ __forceinline__ float leaky02(float x) {
    return x >= 0.f ? x : 0.2f * x;
}

// ---------------------------------------------------------------------------
// CSR build
__global__ __launch_bounds__(256) void deg_init_kernel(int* __restrict__ deg, int N)
{
    int i = blockIdx.x * 256 + threadIdx.x;
    if (i < N) deg[i] = 1;  // self loop
}

__global__ __launch_bounds__(256) void deg_count_kernel(
    const int* __restrict__ dst, int* __restrict__ deg, int E)
{
    int i = blockIdx.x * 256 + threadIdx.x;
    if (i < E) atomicAdd(&deg[dst[i]], 1);
}

#define SCAN_TILE 1024

__global__ __launch_bounds__(256) void scanA_kernel(
    const int* __restrict__ deg, int* __restrict__ bsum, int N)
{
    __shared__ int ws[4];
    int b = blockIdx.x, t = threadIdx.x;
    int base = b * SCAN_TILE + t * 4;
    int s = 0;
#pragma unroll
    for (int k = 0; k < 4; ++k) {
        int i = base + k;
        if (i < N) s += deg[i];
    }
#pragma unroll
    for (int m = 32; m >= 1; m >>= 1) s += __shfl_xor(s, m, 64);
    if ((t & 63) == 0) ws[t >> 6] = s;
    __syncthreads();
    if (t == 0) bsum[b] = ws[0] + ws[1] + ws[2] + ws[3];
}

__global__ __launch_bounds__(1024) void scanB_kernel(
    int* __restrict__ bsum, int* __restrict__ bpre, int* __restrict__ rowp,
    int NB, int N)
{
    __shared__ int sh[1024];
    int t = threadIdx.x;
    int v = (t < NB) ? bsum[t] : 0;
    sh[t] = v;
    __syncthreads();
    for (int off = 1; off < 1024; off <<= 1) {
        int u = (t >= off) ? sh[t - off] : 0;
        __syncthreads();
        sh[t] += u;
        __syncthreads();
    }
    if (t < NB) bpre[t] = sh[t] - v;          // exclusive prefix
    if (t == 1023) rowp[N] = sh[1023];        // total
}

__global__ __launch_bounds__(256) void scanC_kernel(
    const int* __restrict__ deg, const int* __restrict__ bpre,
    int* __restrict__ rowp, int* __restrict__ cur, int N)
{
    __shared__ int sh[256];
    int b = blockIdx.x, t = threadIdx.x;
    int base = b * SCAN_TILE + t * 4;
    int v[4];
#pragma unroll
    for (int k = 0; k < 4; ++k) {
        int i = base + k;
        v[k] = (i < N) ? deg[i] : 0;
    }
    int tsum = v[0] + v[1] + v[2] + v[3];
    sh[t] = tsum;
    __syncthreads();
    for (int off = 1; off < 256; off <<= 1) {
        int u = (t >= off) ? sh[t - off] : 0;
        __syncthreads();
        sh[t] += u;
        __syncthreads();
    }
    int pre = bpre[b] + sh[t] - tsum;
#pragma unroll
    for (int k = 0; k < 4; ++k) {
        int i = base + k;
        if (i < N) { rowp[i] = pre; cur[i] = pre; }
        pre += v[k];
    }
}

__global__ __launch_bounds__(256) void scatter_kernel(
    const int* __restrict__ src, const int* __restrict__ dst,
    int* __restrict__ cur, int* __restrict__ col, int E, int N)
{
    int i = blockIdx.x * 256 + threadIdx.x;
    if (i < E) {
        int p = atomicAdd(&cur[dst[i]], 1);
        col[p] = src[i];
    } else if (i < E + N) {
        int v = i - E;
        int p = atomicAdd(&cur[v], 1);
        col[p] = v;  // self loop
    }
}

// ---------------------------------------------------------------------------
// Layer-0 rank-1 precompute
__global__ __launch_bounds__(128) void rank1_prep_kernel(
    const float* __restrict__ lW, const float* __restrict__ lb,
    const float* __restrict__ W0, const float* __restrict__ al,
    const float* __restrict__ ar, float* __restrict__ c1,
    float* __restrict__ c2, float* __restrict__ prm)
{
    int j = threadIdx.x;
    float s1 = 0.f, s2 = 0.f;
    for (int d = 0; d < 128; ++d) {
        float wv = W0[j * 128 + d];
        s1 += lW[d] * wv;
        s2 += lb[d] * wv;
    }
    c1[j] = s1; c2[j] = s2;
    __shared__ float sh1[128], sh2[128], sh3[128], sh4[128];
    sh1[j] = s1 * al[j]; sh2[j] = s2 * al[j];
    sh3[j] = s1 * ar[j]; sh4[j] = s2 * ar[j];
    __syncthreads();
    if (j < 4) {
        float p = 0.f, q = 0.f, r = 0.f, s = 0.f;
        for (int f = 0; f < 32; ++f) {
            p += sh1[j * 32 + f]; q += sh2[j * 32 + f];
            r += sh3[j * 32 + f]; s += sh4[j * 32 + f];
        }
        prm[j] = p; prm[4 + j] = q; prm[8 + j] = r; prm[12 + j] = s;
    }
}

// h0[n,j] = w[n]*c1[j] + c2[j]; el0[n,h] = w[n]*pl[h]+ql[h]; er0 likewise.
__global__ __launch_bounds__(256) void rank1_apply_kernel(
    const float* __restrict__ w, const float* __restrict__ c1,
    const float* __restrict__ c2, const float* __restrict__ prm,
    float* __restrict__ h, float* __restrict__ el, float* __restrict__ er, int N)
{
    int i = blockIdx.x * 256 + threadIdx.x;
    int n = i >> 5, k = i & 31;
    if (n >= N) return;
    float wn = w[n];
    float4 a = *reinterpret_cast<const float4*>(&c1[k * 4]);
    float4 b = *reinterpret_cast<const float4*>(&c2[k * 4]);
    float4 o = make_float4(wn * a.x + b.x, wn * a.y + b.y,
                           wn * a.z + b.z, wn * a.w + b.w);
    *reinterpret_cast<float4*>(&h[(size_t)n * 128 + k * 4]) = o;
    if (k == 0) {
        float4 pl = *reinterpret_cast<const float4*>(&prm[0]);
        float4 ql = *reinterpret_cast<const float4*>(&prm[4]);
        float4 pr = *reinterpret_cast<const float4*>(&prm[8]);
        float4 qr = *reinterpret_cast<const float4*>(&prm[12]);
        float4 e1 = make_float4(wn * pl.x + ql.x, wn * pl.y + ql.y,
                                wn * pl.z + ql.z, wn * pl.w + ql.w);
        float4 e2 = make_float4(wn * pr.x + qr.x, wn * pr.y + qr.y,
                                wn * pr.z + qr.z, wn * pr.w + qr.w);
        *reinterpret_cast<float4*>(&el[(size_t)n * 4]) = e1;
        *reinterpret_cast<float4*>(&er[(size_t)n * 4]) = e2;
    }
}

// ---------------------------------------------------------------------------
// GEMM + fused el/er (layers 1,2): h[n,j] = sum_d leaky0.01(x[n,d])*W[j,d]
// 64x128 tile, BK=32, 256 threads, 8x4 micro-tile (R2 structure).
// Pads 73/133 make the transposed staging writes 2-way-bank-free:
//   xs stride 73 %32==9 -> lc*9 spans {0,4,...,28}; +lr(0..7) = 32 banks x2
//   wsh stride 133 %32==5 -> lc*5 spans {0,20,8,28,16,4,24,12}; +lr = x2
// el/er epilogue: head = tx>>3; reduce over 8 lanes (tx&7) via shfl_xor.
__global__ __launch_bounds__(256) void gemm_fused_kernel(
    const float* __restrict__ x, const float* __restrict__ W,
    const float* __restrict__ al, const float* __restrict__ ar,
    float* __restrict__ h, float* __restrict__ el, float* __restrict__ er,
    int N)
{
    __shared__ float xs[32][73];     // [d][row]
    __shared__ float wsh[32][133];   // [d][j]
    const int tid = threadIdx.x;
    const int m0 = blockIdx.x * 64;
    const int tx = tid & 31;   // col group: j = tx*4 .. +3
    const int ty = tid >> 5;   // row group: n = ty*8 .. +7

    float acc[8][4];
#pragma unroll
    for (int r = 0; r < 8; ++r)
#pragma unroll
        for (int c = 0; c < 4; ++c) acc[r][c] = 0.f;

    const int lr = tid >> 3;          // 0..31
    const int lc = (tid & 7) * 4;     // 0,4,...,28

    for (int k0 = 0; k0 < 128; k0 += 32) {
        // stage x tile (64 x 32) transposed, with leaky(0.01)
#pragma unroll
        for (int p = 0; p < 2; ++p) {
            int row = m0 + lr + p * 32;
            float4 v = make_float4(0.f, 0.f, 0.f, 0.f);
            if (row < N) v = *reinterpret_cast<const float4*>(&x[(size_t)row * 128 + k0 + lc]);
            v.x = v.x >= 0.f ? v.x : 0.01f * v.x;
            v.y = v.y >= 0.f ? v.y : 0.01f * v.y;
            v.z = v.z >= 0.f ? v.z : 0.01f * v.z;
            v.w = v.w >= 0.f ? v.w : 0.01f * v.w;
            xs[lc + 0][lr + p * 32] = v.x;
            xs[lc + 1][lr + p * 32] = v.y;
            xs[lc + 2][lr + p * 32] = v.z;
            xs[lc + 3][lr + p * 32] = v.w;
        }
        // stage W tile (128 x 32) transposed
#pragma unroll
        for (int p = 0; p < 4; ++p) {
            int j = p * 32 + lr;
            float4 v = *reinterpret_cast<const float4*>(&W[(size_t)j * 128 + k0 + lc]);
            wsh[lc + 0][j] = v.x;
            wsh[lc + 1][j] = v.y;
            wsh[lc + 2][j] = v.z;
            wsh[lc + 3][j] = v.w;
        }
        __syncthreads();

#pragma unroll
        for (int d = 0; d < 32; ++d) {
            const float4 b  = *reinterpret_cast<const float4*>(&wsh[d][tx * 4]);
            const float4 a0 = *reinterpret_cast<const float4*>(&xs[d][ty * 8]);
            const float4 a1 = *reinterpret_cast<const float4*>(&xs[d][ty * 8 + 4]);
            const float av[8] = {a0.x, a0.y, a0.z, a0.w, a1.x, a1.y, a1.z, a1.w};
            const float bv[4] = {b.x, b.y, b.z, b.w};
#pragma unroll
            for (int r = 0; r < 8; ++r)
#pragma unroll
                for (int c = 0; c < 4; ++c) acc[r][c] += av[r] * bv[c];
        }
        __syncthreads();
    }

    // epilogue: store h + fused el/er
    const int head = tx >> 3;         // 4 cols lie in one head (tx*4 .. +3)
    const float4 alv = *reinterpret_cast<const float4*>(&al[tx * 4]);
    const float4 arv = *reinterpret_cast<const float4*>(&ar[tx * 4]);
#pragma unroll
    for (int r = 0; r < 8; ++r) {
        int row = m0 + ty * 8 + r;
        bool ok = row < N;
        if (ok) {
            float4 v = make_float4(acc[r][0], acc[r][1], acc[r][2], acc[r][3]);
            *reinterpret_cast<float4*>(&h[(size_t)row * 128 + tx * 4]) = v;
        }
        float elp = acc[r][0] * alv.x + acc[r][1] * alv.y
                  + acc[r][2] * alv.z + acc[r][3] * alv.w;
        float erp = acc[r][0] * arv.x + acc[r][1] * arv.y
                  + acc[r][2] * arv.z + acc[r][3] * arv.w;
#pragma unroll
        for (int d = 1; d <= 4; d <<= 1) {
            elp += __shfl_xor(elp, d, 64);
            erp += __shfl_xor(erp, d, 64);
        }
        if (ok && (tx & 7) == 0) {
            el[(size_t)row * 4 + head] = elp;
            er[(size_t)row * 4 + head] = erp;
        }
    }
}

// ---------------------------------------------------------------------------
// Fused softmax-stats + gather + (optional) prediction epilogue.
// One wave per node (head-quartered Phase A, direct-load Phase B).
__global__ __launch_bounds__(256) void agg_fused_kernel(
    const float* __restrict__ h, const float* __restrict__ el,
    const float* __restrict__ er, const int* __restrict__ rowp,
    const int* __restrict__ col, const float* __restrict__ bias,
    float* __restrict__ xout, const float* __restrict__ pW,
    const float* __restrict__ pb, float* __restrict__ logits,
    int N, int last)
{
    int v = blockIdx.x * 4 + (threadIdx.x >> 6);
    int lane = threadIdx.x & 63;
    if (v >= N) return;
    const int r0 = rowp[v], r1 = rowp[v + 1];
    const int deg = r1 - r0;

    // ---- Phase A: per-head online softmax stats
    const int qh  = lane >> 4;
    const int j16 = lane & 15;
    const float erq = er[(size_t)v * 4 + qh];

    float m_l = -INFINITY, s_l = 0.f;
    for (int jj = j16; jj < deg; jj += 16) {
        int u = col[r0 + jj];
        float e = leaky02(el[(size_t)u * 4 + qh] + erq);
        if (e > m_l) { s_l = s_l * __expf(m_l - e) + 1.f; m_l = e; }
        else         { s_l += __expf(e - m_l); }
    }
#pragma unroll
    for (int d = 1; d <= 8; d <<= 1) {
        float m2 = __shfl_xor(m_l, d, 64);
        float s2 = __shfl_xor(s_l, d, 64);
        float nm = fmaxf(m_l, m2);
        s_l = (s_l > 0.f ? s_l * __expf(m_l - nm) : 0.f)
            + (s2  > 0.f ? s2  * __expf(m2  - nm) : 0.f);
        m_l = nm;
    }
    const float is_l = 1.f / s_l;

    // ---- Phase B: gather, 4 edges in flight (quarter-wave per edge)
    const int q = lane >> 4, l16 = lane & 15, f0 = l16 * 4, hA = l16 >> 3;
    const float mA  = __shfl(m_l,  hA * 16, 64);
    const float isA = __shfl(is_l, hA * 16, 64);
    const float mB  = __shfl(m_l,  (hA + 2) * 16, 64);
    const float isB = __shfl(is_l, (hA + 2) * 16, 64);
    const float erA = er[(size_t)v * 4 + hA];
    const float erB = er[(size_t)v * 4 + 2 + hA];

    float4 acc0 = make_float4(0.f, 0.f, 0.f, 0.f);
    float4 acc1 = make_float4(0.f, 0.f, 0.f, 0.f);

    for (int j = r0 + q; j < r1; j += 4) {
        int u = col[j];
        float eA = leaky02(el[(size_t)u * 4 + hA] + erA);
        float eB = leaky02(el[(size_t)u * 4 + 2 + hA] + erB);
        float aA = __expf(eA - mA) * isA;
        float aB = __expf(eB - mB) * isB;
        const float4 v0 = *reinterpret_cast<const float4*>(&h[(size_t)u * 128 + f0]);
        const float4 v1 = *reinterpret_cast<const float4*>(&h[(size_t)u * 128 + 64 + f0]);
        acc0.x += aA * v0.x; acc0.y += aA * v0.y;
        acc0.z += aA * v0.z; acc0.w += aA * v0.w;
        acc1.x += aB * v1.x; acc1.y += aB * v1.y;
        acc1.z += aB * v1.z; acc1.w += aB * v1.w;
    }

#pragma unroll
    for (int d = 16; d <= 32; d <<= 1) {
        acc0.x += __shfl_xor(acc0.x, d, 64);
        acc0.y += __shfl_xor(acc0.y, d, 64);
        acc0.z += __shfl_xor(acc0.z, d, 64);
        acc0.w += __shfl_xor(acc0.w, d, 64);
        acc1.x += __shfl_xor(acc1.x, d, 64);
        acc1.y += __shfl_xor(acc1.y, d, 64);
        acc1.z += __shfl_xor(acc1.z, d, 64);
        acc1.w += __shfl_xor(acc1.w, d, 64);
    }

    if (last) {
        float part = 0.f;
        if (lane < 16) {
            float4 b0 = *reinterpret_cast<const float4*>(&bias[f0]);
            float4 b1 = *reinterpret_cast<const float4*>(&bias[64 + f0]);
            float4 p0 = *reinterpret_cast<const float4*>(&pW[f0]);
            float4 p1 = *reinterpret_cast<const float4*>(&pW[64 + f0]);
            part = (acc0.x + b0.x) * p0.x + (acc0.y + b0.y) * p0.y
                 + (acc0.z + b0.z) * p0.z + (acc0.w + b0.w) * p0.w
                 + (acc1.x + b1.x) * p1.x + (acc1.y + b1.y) * p1.y
                 + (acc1.z + b1.z) * p1.z + (acc1.w + b1.w) * p1.w;
        }
#pragma unroll
        for (int d = 8; d >= 1; d >>= 1) part += __shfl_xor(part, d, 64);
        if (lane == 0) logits[v] = part + pb[0];
    } else {
        if (lane < 16) {
            float4 b0 = *reinterpret_cast<const float4*>(&bias[f0]);
            float4 b1 = *reinterpret_cast<const float4*>(&bias[64 + f0]);
            acc0.x += b0.x; acc0.y += b0.y; acc0.z += b0.z; acc0.w += b0.w;
            acc1.x += b1.x; acc1.y += b1.y; acc1.z += b1.z; acc1.w += b1.w;
            *reinterpret_cast<float4*>(&xout[(size_t)v * 128 + f0])      = acc0;
            *reinterpret_cast<float4*>(&xout[(size_t)v * 128 + 64 + f0]) = acc1;
        }
    }
}

// ---------------------------------------------------------------------------
extern "C" void kernel_launch(void* const* d_in, const int* in_sizes, int n_in,
                              void* d_out, int out_size, void* d_ws, size_t ws_size,
                              hipStream_t stream)
{
    const float* weights = (const float*)d_in[0];
    const float* lin_W   = (const float*)d_in[1];
    const float* lin_b   = (const float*)d_in[2];
    const float* fc_W    = (const float*)d_in[3];
    const float* attn_l  = (const float*)d_in[4];
    const float* attn_r  = (const float*)d_in[5];
    const float* conv_b  = (const float*)d_in[6];
    const float* pred_W  = (const float*)d_in[7];
    const float* pred_b  = (const float*)d_in[8];
    const int*   src     = (const int*)d_in[9];
    const int*   dst     = (const int*)d_in[10];

    const int N = in_sizes[0];
    const int E = in_sizes[9];
    const int NB = (N + SCAN_TILE - 1) / SCAN_TILE;

    // workspace layout (16B-aligned float4 sections first)
    float* x   = (float*)d_ws;                   // N*128
    float* h   = x + (size_t)N * 128;            // N*128
    float* el  = h + (size_t)N * 128;            // N*4
    float* er  = el + (size_t)N * 4;             // N*4
    float* c1  = er + (size_t)N * 4;             // 128
    float* c2  = c1 + 128;                       // 128
    float* prm = c2 + 128;                       // 16
    int*   deg  = (int*)(prm + 16);              // N
    int*   rowp = deg + N;                       // N+1
    int*   cur  = rowp + (N + 1);                // N
    int*   col  = cur + N;                       // E+N
    int*   bsum = col + (E + N);                 // NB
    int*   bpre = bsum + NB;                     // NB

    // CSR build (fresh every call: ws is re-poisoned)
    deg_init_kernel<<<(N + 255) / 256, 256, 0, stream>>>(deg, N);
    deg_count_kernel<<<(E + 255) / 256, 256, 0, stream>>>(dst, deg, E);
    scanA_kernel<<<NB, 256, 0, stream>>>(deg, bsum, N);
    scanB_kernel<<<1, 1024, 0, stream>>>(bsum, bpre, rowp, NB, N);
    scanC_kernel<<<NB, 256, 0, stream>>>(deg, bpre, rowp, cur, N);
    scatter_kernel<<<(E + N + 255) / 256, 256, 0, stream>>>(src, dst, cur, col, E, N);

    // Layer 0 via rank-1 identity
    rank1_prep_kernel<<<1, 128, 0, stream>>>(lin_W, lin_b, fc_W, attn_l, attn_r,
                                             c1, c2, prm);
    rank1_apply_kernel<<<((size_t)N * 32 + 255) / 256, 256, 0, stream>>>(
        weights, c1, c2, prm, h, el, er, N);
    agg_fused_kernel<<<(N + 3) / 4, 256, 0, stream>>>(
        h, el, er, rowp, col, conv_b, x, pred_W, pred_b, (float*)d_out, N, 0);

    // Layers 1, 2 (gemm with fused el/er epilogue)
    for (int l = 1; l < 3; ++l) {
        gemm_fused_kernel<<<(N + 63) / 64, 256, 0, stream>>>(
            x, fc_W + (size_t)l * 128 * 128,
            attn_l + l * 128, attn_r + l * 128,
            h, el, er, N);
        agg_fused_kernel<<<(N + 3) / 4, 256, 0, stream>>>(
            h, el, er, rowp, col, conv_b + l * 128, x, pred_W, pred_b,
            (float*)d_out, N, l == 2 ? 1 : 0);
    }
}